// Round 4
// baseline (747.744 us; speedup 1.0000x reference)
//
#include <hip/hip_runtime.h>
#include <hip/hip_bf16.h>
#include <stdint.h>

typedef __attribute__((__ext_vector_type__(8))) __bf16 bf16x8;
typedef __attribute__((__ext_vector_type__(2))) __bf16 bf16x2;
typedef __attribute__((__ext_vector_type__(4))) float  f32x4;
typedef __attribute__((__ext_vector_type__(8))) int    v8i;

// Fixed MX scales (e8m0): A quantized x2^8 -> scale byte 119 (2^-8),
// B quantized x2^6 -> scale byte 121 (2^-6). Byte replicated so any
// op_sel byte selection reads the same value.
#define SCALE_A_DW 0x77777777
#define SCALE_B_DW 0x79797979

// async 16B global->LDS (dest = wave-uniform base + lane*16)
__device__ __forceinline__ void gl_lds16(const void* g, void* l) {
  __builtin_amdgcn_global_load_lds(
      (__attribute__((address_space(1))) void*)(uintptr_t)g,
      (__attribute__((address_space(3))) void*)(unsigned)(uintptr_t)l,
      16, 0, 0);
}

// ---- fused prep: stats / labels / pack_avg / pack_wsp / Aav-zero-row -------
__global__ __launch_bounds__(256) void k_prep(
    const float* __restrict__ x, float* __restrict__ stats,
    const float* __restrict__ seg, int* __restrict__ labels,
    const float* __restrict__ cgw, const float* __restrict__ cbw,
    float* __restrict__ wpa,
    const float* __restrict__ ssw, __bf16* __restrict__ wspb,
    __bf16* __restrict__ Aav) {
  __shared__ __align__(16) char smem[16*401*4];
  int blk = blockIdx.x;
  if (blk < 2048) {                       // ---- instance-norm stats
    int bc = blk;
    const float4* p = (const float4*)(x + (size_t)bc * 4096);
    float s = 0.f, ss = 0.f;
    for (int i = threadIdx.x; i < 1024; i += 256) {
      float4 v = p[i];
      s  += v.x + v.y + v.z + v.w;
      ss += v.x*v.x + v.y*v.y + v.z*v.z + v.w*v.w;
    }
    #pragma unroll
    for (int o = 32; o > 0; o >>= 1) { s += __shfl_down(s, o); ss += __shfl_down(ss, o); }
    float* sh = (float*)smem;
    int wv = threadIdx.x >> 6;
    if ((threadIdx.x & 63) == 0) { sh[wv] = s; sh[4 + wv] = ss; }
    __syncthreads();
    if (threadIdx.x == 0) {
      float S = sh[0]+sh[1]+sh[2]+sh[3], SS = sh[4]+sh[5]+sh[6]+sh[7];
      float m = S * (1.f/4096.f);
      float var = SS * (1.f/4096.f) - m*m;
      stats[bc] = m;
      stats[2048 + bc] = rsqrtf(var + 1e-5f);
    }
  } else if (blk < 2176) {                // ---- labels (last one-hot j)
    int idx = (blk - 2048)*256 + threadIdx.x;       // 0..32767
    int b = idx >> 12, pix = idx & 4095;
    const float* p = seg + (size_t)b*19*4096 + pix;
    int lab = -1;
    for (int j = 0; j < 19; ++j) if (p[(size_t)j*4096] > 0.f) lab = j;
    labels[idx] = lab;
  } else if (blk < 3200) {                // ---- pack avg weights wpa[k5][c][n]
    int bid = blk - 2176;
    float* s = (float*)smem;
    int n0 = (bid & 31) * 16, c0 = (bid >> 5) * 16;
    for (int i = threadIdx.x; i < 6400; i += 256) {
      int nn = i / 400, qq = i % 400;
      int n = n0 + nn;
      const float* src = (n < 256) ? cgw + (size_t)n*12800 : cbw + (size_t)(n-256)*12800;
      s[nn*401 + qq] = src[c0*25 + qq];
    }
    __syncthreads();
    for (int i = threadIdx.x; i < 6400; i += 256) {
      int nn = i & 15, rest = i >> 4;
      int k5 = rest % 25, cc = rest / 25;
      wpa[((size_t)k5*512 + c0 + cc)*512 + n0 + nn] = s[nn*401 + cc*25 + k5];
    }
  } else if (blk < 4200) {                // ---- pack shared weights (j=19 zero)
    int idx = (blk - 3200)*256 + threadIdx.x;       // < 256000
    int o = idx & 511, k5 = (idx >> 9) % 25, j = idx / 12800;
    wspb[idx] = (j < 19) ? (__bf16)ssw[((size_t)o*19 + j)*25 + k5] : (__bf16)0.f;
  } else {                                // ---- Aav zero row 3800
    ((unsigned*)(Aav + 3800ull*512))[threadIdx.x] = 0;   // 256 dwords = 1024 B
  }
}

// ---------------- mu[b,j,e] = relu(sum_d sc[b,j,d]*fc_w[j,e,d] + fc_b) ------
__global__ __launch_bounds__(512) void k_mu(const float* __restrict__ sc,
                                            const float* __restrict__ fcw,
                                            const float* __restrict__ fcb,
                                            float* __restrict__ mu) {
  int b = blockIdx.x / 19, j = blockIdx.x % 19;
  __shared__ float s[512];
  s[threadIdx.x] = sc[(b*19 + j)*512 + threadIdx.x];
  __syncthreads();
  int e = threadIdx.x;
  const float4* w4 = (const float4*)(fcw + ((size_t)(j*512 + e))*512);
  const float4* s4 = (const float4*)s;
  float acc = 0.f;
  for (int d = 0; d < 128; ++d) {
    float4 w = w4[d], v = s4[d];
    acc += w.x*v.x + w.y*v.y + w.z*v.z + w.w*v.w;
  }
  acc += fcb[j*512 + e];
  mu[(b*19 + j)*512 + e] = fmaxf(acc, 0.f);
}

// ---- pack spade weights -> fp8 e4m3, fixed scale x2^6: wq[k5][n][c] --------
__global__ __launch_bounds__(256) void k_pack_spade(
    const float* __restrict__ g, const float* __restrict__ bt,
    uint8_t* __restrict__ wq) {
  int n = blockIdx.x;                               // 0..511
  const float* src = (n < 256) ? g + (size_t)n*12800 : bt + (size_t)(n-256)*12800;
  __shared__ float s[12800];
  for (int i = threadIdx.x; i < 12800; i += 256) s[i] = src[i];
  __syncthreads();
  int t = threadIdx.x;
  for (int k5 = 0; k5 < 25; ++k5) {
    float w0 = s[(2*t)*25 + k5] * 64.f, w1 = s[(2*t+1)*25 + k5] * 64.f;
    int pk = __builtin_amdgcn_cvt_pk_fp8_f32(w0, w1, 0, false);
    *(unsigned short*)(wq + ((size_t)k5*512 + n)*512 + 2*t) = (unsigned short)pk;
  }
}

// ---- A[b,j,k5,n] = sum_c mu[b,j,c]*wpa[k5][c][n]  (mu via scalar loads) ----
__global__ __launch_bounds__(512) void k_A_avg(const float* __restrict__ mu,
                                               const float* __restrict__ wpa,
                                               __bf16* __restrict__ A) {
  int b = blockIdx.x / 25, k5 = blockIdx.x % 25;
  int n = threadIdx.x;
  const float* wp = wpa + (size_t)k5*262144 + n;
  const float* mub = mu + b*19*512;                 // wave-uniform rows -> s_load
  float acc[19];
  #pragma unroll
  for (int j = 0; j < 19; ++j) acc[j] = 0.f;
  for (int c = 0; c < 512; ++c) {
    float w = wp[(size_t)c*512];
    #pragma unroll
    for (int j = 0; j < 19; ++j) acc[j] += mub[j*512 + c] * w;
  }
  #pragma unroll
  for (int j = 0; j < 19; ++j)
    A[((size_t)((b*19 + j)*25 + k5))*512 + n] = (__bf16)acc[j];
}

// ---- actv: debranched gather -> fp8 e4m3 (x2^8) NHWC padded ----------------
// Writes its own zero borders (rows hp<2, hp>=66 and cols wp in {0,1,66,67}).
__global__ void k_actv(const int* __restrict__ labels, const __bf16* __restrict__ wsp,
                       const float* __restrict__ ssb, uint8_t* __restrict__ actv) {
  int b = blockIdx.x / 68, hp = blockIdx.x % 68;
  int t = threadIdx.x;
  size_t rowbase = ((size_t)b*68 + hp)*68;          // padded pixel index base
  if (hp < 2 || hp >= 66) {                         // full zero row
    unsigned* dp = (unsigned*)(actv + rowbase*512);
    for (int i = t; i < 8704; i += 256) dp[i] = 0;
    return;
  }
  int h = hp - 2;
  __shared__ int lab[5*68];
  for (int i = t; i < 5*68; i += 256) {
    int dh = i / 68, xx = i % 68;
    int hh = h + dh - 2, ww = xx - 2;
    int l = 19;
    if (hh >= 0 && hh < 64 && ww >= 0 && ww < 64) {
      int l0 = labels[b*4096 + hh*64 + ww];
      if (l0 >= 0) l = l0;
    }
    lab[i] = l;
  }
  {                                                 // left/right border pixels
    unsigned* dp = (unsigned*)(actv + rowbase*512);
    dp[t] = 0; dp[66*128 + t] = 0;                  // pixels 0,1 and 66,67
  }
  __syncthreads();
  float bs0 = ssb[2*t], bs1 = ssb[2*t + 1];
  for (int w = 0; w < 64; ++w) {
    float a0 = bs0, a1 = bs1;
    #pragma unroll
    for (int tap = 0; tap < 25; ++tap) {
      int l = lab[(tap/5)*68 + w + (tap%5)];        // wave-uniform
      bf16x2 v = *(const bf16x2*)(wsp + (size_t)(l*25 + tap)*512 + 2*t);
      a0 += (float)v[0]; a1 += (float)v[1];
    }
    a0 = fmaxf(a0, 0.f) * 256.f;
    a1 = fmaxf(a1, 0.f) * 256.f;
    int pk = __builtin_amdgcn_cvt_pk_fp8_f32(a0, a1, 0, false);
    *(unsigned short*)(actv + (rowbase + 2 + w)*512 + 2*t) = (unsigned short)pk;
  }
}

// ---- implicit-GEMM conv, MXFP8 fixed-scale: M=32768, N=512, K=12800 --------
// 256x256 tile, 8 waves (wave tile 128x64), BK=128, counted vmcnt (T4).
// R4: B operand bypasses LDS entirely -- each B-frag is 32 contiguous bytes
// in global (L2-resident), loaded straight to VGPRs one chunk ahead
// (register double-buffer, T14). LDS now holds only A (2x32 KB), cutting
// LDS-pipe demand below the MFMA-pipe floor (1790 vs 2208 cy/chunk/CU).
__global__ __launch_bounds__(512) void k_conv(
    const uint8_t* __restrict__ actv, const uint8_t* __restrict__ wq,
    const float* __restrict__ sgb, const float* __restrict__ sbb,
    __bf16* __restrict__ gbs) {
  __shared__ __align__(16) uint8_t ldsA[2][32768];  // 256 rows x 128 B
  const int tid = threadIdx.x, wv = tid >> 6, lane = tid & 63;
  const int l15 = lane & 15, q = lane >> 4;
  const int m0 = blockIdx.x * 256, n0 = blockIdx.y * 256;
  const int b = m0 >> 12;

  int aoff[4], ldst[4];                             // staging offsets (bytes)
  #pragma unroll
  for (int i = 0; i < 4; ++i) {
    int p = i*512 + tid;                            // 16B slot 0..2047
    int r = p >> 3, pc = p & 7;
    int cl = pc ^ (r & 7);                          // logical chunk fetched
    int pix = (m0 + r) & 4095;
    int h = pix >> 6, w = pix & 63;
    aoff[i] = ((b*68 + h)*68 + w)*512 + cl*16;
    ldst[i] = i*8192 + wv*1024;                     // wave-uniform LDS base
  }

  const int wm = (wv >> 2) * 128, wn = (wv & 3) * 64;
  // per-lane global base for B-frags: row n = n0+wn+ni*16+l15, bytes q*32..
  const uint8_t* wqb = wq + (size_t)(n0 + wn + l15)*512 + q*32;
  f32x4 acc[8][4] = {};

  // stage A K-chunk t into LDS buffer `buf` (4 vmem/wave)
  auto stageA = [&](int t, int buf) {
    int k5 = t >> 2, kc = t & 3;
    int a_k = ((k5/5)*68 + (k5%5))*512 + kc*128;
    uint8_t* la = &ldsA[buf][0];
    #pragma unroll
    for (int i = 0; i < 4; ++i)
      gl_lds16(actv + aoff[i] + a_k, la + ldst[i]);
  };

  // load B-frags for chunk t straight to regs (8 vmem/wave: 4x 32B)
  auto loadB = [&](int t, v8i* o) {
    const uint8_t* p = wqb + (t >> 2)*262144 + (t & 3)*128;
    #pragma unroll
    for (int ni = 0; ni < 4; ++ni)
      o[ni] = *(const v8i*)(p + ni*16*512);
  };

  // compute K-chunk from LDS buffer `buf` + B regs (call with literal 0/1)
  auto compute = [&](int buf, const v8i* bfr) {
    __builtin_amdgcn_s_setprio(1);
    #pragma unroll
    for (int mi = 0; mi < 8; ++mi) {
      int row = wm + mi*16 + l15;
      const uint8_t* base = &ldsA[buf][row*128];
      union { v8i v; uint4 u[2]; } tt;
      tt.u[0] = *(const uint4*)(base + ((2*q    ) ^ (row & 7))*16);
      tt.u[1] = *(const uint4*)(base + ((2*q + 1) ^ (row & 7))*16);
      v8i af = tt.v;
      #pragma unroll
      for (int ni = 0; ni < 4; ++ni)
        acc[mi][ni] = __builtin_amdgcn_mfma_scale_f32_16x16x128_f8f6f4(
            af, bfr[ni], acc[mi][ni], 0, 0, 0, SCALE_A_DW, 0, SCALE_B_DW);
    }
    __builtin_amdgcn_s_setprio(0);
  };

  v8i bA[4], bB[4];
  stageA(0, 0); loadB(0, bA);
  stageA(1, 1); loadB(1, bB);                       // 24 vmem in flight
  #pragma unroll 1
  for (int t = 0; t < 98; t += 2) {
    asm volatile("s_waitcnt vmcnt(12)" ::: "memory");   // A(t),B(t) done
    __builtin_amdgcn_s_barrier();
    __builtin_amdgcn_sched_barrier(0);
    compute(0, bA);
    __builtin_amdgcn_sched_barrier(0);
    __builtin_amdgcn_s_barrier();
    __builtin_amdgcn_sched_barrier(0);
    stageA(t + 2, 0); loadB(t + 2, bA);
    __builtin_amdgcn_sched_barrier(0);
    asm volatile("s_waitcnt vmcnt(12)" ::: "memory");   // A(t+1),B(t+1) done
    __builtin_amdgcn_s_barrier();
    __builtin_amdgcn_sched_barrier(0);
    compute(1, bB);
    __builtin_amdgcn_sched_barrier(0);
    __builtin_amdgcn_s_barrier();
    __builtin_amdgcn_sched_barrier(0);
    stageA(t + 3, 1); loadB(t + 3, bB);
    __builtin_amdgcn_sched_barrier(0);
  }
  // tail: chunk 98 (buf0; chunk 99's 12 still in flight), then chunk 99
  asm volatile("s_waitcnt vmcnt(12)" ::: "memory");
  __builtin_amdgcn_s_barrier();
  __builtin_amdgcn_sched_barrier(0);
  compute(0, bA);
  asm volatile("s_waitcnt vmcnt(0)" ::: "memory");
  __builtin_amdgcn_s_barrier();
  __builtin_amdgcn_sched_barrier(0);
  compute(1, bB);

  // epilogue: D[row=q*4+r][col=l15]; NHWC store gbs[m][n] (+spade bias)
  #pragma unroll
  for (int ni = 0; ni < 4; ++ni) {
    int n = n0 + wn + ni*16 + l15;
    float bias = (n < 256) ? sgb[n] : sbb[n - 256];
    #pragma unroll
    for (int mi = 0; mi < 8; ++mi) {
      int m = m0 + wm + mi*16 + q*4;
      size_t base = (size_t)m*512 + n;
      #pragma unroll
      for (int r = 0; r < 4; ++r)
        gbs[base + (size_t)r*512] = (__bf16)(acc[mi][ni][r] + bias);
    }
  }
}

// ---- fused avg-gather + blend/instance-norm/NCHW-store ---------------------
// Phase 1 (thread = channel pair): 25-tap gather of gamma/beta_avg for 16
// pixels -> LDS; stage matching gbs tile -> LDS (coalesced).
// Phase 2 (thread = channel): blend avg/spade, normalize x, write out NCHW.
__global__ __launch_bounds__(256) void k_gf(
    const int* __restrict__ labels, const __bf16* __restrict__ A,
    const float* __restrict__ cgb, const float* __restrict__ cbb,
    const __bf16* __restrict__ gbs, const float* __restrict__ x,
    const float* __restrict__ stats, const float* __restrict__ blg,
    const float* __restrict__ blb, float* __restrict__ out) {
  int wt = blockIdx.x & 3, h = (blockIdx.x >> 2) & 63, b = blockIdx.x >> 8;
  int w0 = wt * 16;
  __shared__ int rowbase[5*20];
  __shared__ __bf16 avg[16][512];
  __shared__ __bf16 spd[16][512];
  for (int i = threadIdx.x; i < 100; i += 256) {
    int dh = i / 20, xx = i % 20;
    int hh = h + dh - 2, ww = w0 + xx - 2;
    int l = (hh >= 0 && hh < 64 && ww >= 0 && ww < 64) ? labels[b*4096 + hh*64 + ww] : -1;
    rowbase[i] = (l >= 0) ? (b*19 + l)*25 : -1;
  }
  __syncthreads();
  int t = threadIdx.x;
  float bs0, bs1;
  if (2*t < 256) { bs0 = cgb[2*t]; bs1 = cgb[2*t + 1]; }
  else           { bs0 = cbb[2*t - 256]; bs1 = cbb[2*t - 255]; }
  size_t pixb = (size_t)b*4096 + h*64 + w0;
  for (int px = 0; px < 16; ++px) {
    float a0 = bs0, a1 = bs1;
    #pragma unroll
    for (int tap = 0; tap < 25; ++tap) {
      int rb = rowbase[(tap/5)*20 + px + (tap%5)];
      int row = (rb >= 0) ? rb + tap : 3800;
      bf16x2 v = *(const bf16x2*)(A + (size_t)row*512 + 2*t);
      a0 += (float)v[0]; a1 += (float)v[1];
    }
    avg[px][2*t]     = (__bf16)a0;
    avg[px][2*t + 1] = (__bf16)a1;
    *(bf16x2*)&spd[px][2*t] = *(const bf16x2*)(gbs + (pixb + px)*512 + 2*t);
  }
  __syncthreads();
  float ga = 1.f / (1.f + expf(-blg[0]));
  float ba = 1.f / (1.f + expf(-blb[0]));
  int c = threadIdx.x;                               // 0..255
  int bc = b*256 + c;
  float mean = stats[bc], rstd = stats[2048 + bc];
  size_t xb = (size_t)bc*4096 + h*64 + w0;
  #pragma unroll
  for (int pq = 0; pq < 4; ++pq) {
    float4 xv = *(const float4*)(x + xb + pq*4);
    float4 ov;
    float* xo = (float*)&xv; float* oo = (float*)&ov;
    #pragma unroll
    for (int j = 0; j < 4; ++j) {
      int px = pq*4 + j;
      float gf  = ga*(float)avg[px][c]       + (1.f - ga)*(float)spd[px][c];
      float bf_ = ba*(float)avg[px][256 + c] + (1.f - ba)*(float)spd[px][256 + c];
      oo[j] = (xo[j] - mean)*rstd*(1.f + gf) + bf_;
    }
    *(float4*)(out + xb + pq*4) = ov;
  }
}

extern "C" void kernel_launch(void* const* d_in, const int* in_sizes, int n_in,
                              void* d_out, int out_size, void* d_ws, size_t ws_size,
                              hipStream_t stream) {
  const float* x    = (const float*)d_in[0];
  const float* seg  = (const float*)d_in[1];
  const float* sc   = (const float*)d_in[2];
  const float* fcw  = (const float*)d_in[3];
  const float* fcb  = (const float*)d_in[4];
  const float* cgw  = (const float*)d_in[5];
  const float* cgb  = (const float*)d_in[6];
  const float* cbw  = (const float*)d_in[7];
  const float* cbb  = (const float*)d_in[8];
  const float* ssw  = (const float*)d_in[9];
  const float* ssb  = (const float*)d_in[10];
  const float* sgw  = (const float*)d_in[11];
  const float* sgb  = (const float*)d_in[12];
  const float* sbw  = (const float*)d_in[13];
  const float* sbb  = (const float*)d_in[14];
  const float* blg  = (const float*)d_in[15];
  const float* blb  = (const float*)d_in[16];
  float* out = (float*)d_out;

  char* ws = (char*)d_ws;
  size_t off = 0;
  auto alloc = [&](size_t bytes) {
    void* p = ws + off; off += (bytes + 255) & ~(size_t)255; return p;
  };
  float*   stats = (float*)alloc(2048ull*2*4);
  int*     labels= (int*)  alloc(32768ull*4);
  float*   mu    = (float*)alloc(77824ull*4);
  __bf16*  Aav   = (__bf16*)alloc((3800ull + 1)*512*2);  // + zero row 3800
  __bf16*  wspb  = (__bf16*)alloc(20ull*25*512*2);       // j=19 zero rows
  float*   wpa   = (float*)alloc(25ull*512*512*4);       // 26.2 MB
  uint8_t* wq    = (uint8_t*)alloc(25ull*512*512);       // 6.6 MB fp8
  uint8_t* actv  = (uint8_t*)alloc(8ull*68*68*512);      // 18.9 MB fp8 NHWC pad
  __bf16*  gbs   = (__bf16*)alloc(8ull*4096*512*2);      // 33.5 MB (NHWC)

  k_prep      <<<4201, 256, 0, stream>>>(x, stats, seg, labels, cgw, cbw, wpa, ssw, wspb, Aav);
  k_mu        <<<152, 512, 0, stream>>>(sc, fcw, fcb, mu);
  k_pack_spade<<<512, 256, 0, stream>>>(sgw, sbw, wq);
  k_A_avg     <<<200, 512, 0, stream>>>(mu, wpa, Aav);
  k_actv      <<<544, 256, 0, stream>>>(labels, wspb, ssb, actv);
  k_conv      <<<dim3(128, 2), 512, 0, stream>>>(actv, wq, sgb, sbb, gbs);
  k_gf        <<<2048, 256, 0, stream>>>(labels, Aav, cgb, cbb, gbs, x, stats, blg, blb, out);
}

// Round 5
// 694.228 us; speedup vs baseline: 1.0771x; 1.0771x over previous
//
#include <hip/hip_runtime.h>
#include <hip/hip_bf16.h>
#include <stdint.h>

typedef __attribute__((__ext_vector_type__(8))) __bf16 bf16x8;
typedef __attribute__((__ext_vector_type__(2))) __bf16 bf16x2;
typedef __attribute__((__ext_vector_type__(4))) float  f32x4;
typedef __attribute__((__ext_vector_type__(16))) float f32x16;
typedef __attribute__((__ext_vector_type__(8))) int    v8i;

// Fixed MX scales (e8m0): A quantized x2^8 -> scale byte 119 (2^-8),
// B quantized x2^6 -> scale byte 121 (2^-6). Byte replicated so any
// op_sel byte selection reads the same value.
#define SCALE_A_DW 0x77777777
#define SCALE_B_DW 0x79797979

// async 16B global->LDS (dest = wave-uniform base + lane*16)
__device__ __forceinline__ void gl_lds16(const void* g, void* l) {
  __builtin_amdgcn_global_load_lds(
      (__attribute__((address_space(1))) void*)(uintptr_t)g,
      (__attribute__((address_space(3))) void*)(unsigned)(uintptr_t)l,
      16, 0, 0);
}

// ---- fused prep: stats / labels / pack_avg / pack_wsp / Aav-zero-row -------
__global__ __launch_bounds__(256) void k_prep(
    const float* __restrict__ x, float* __restrict__ stats,
    const float* __restrict__ seg, int* __restrict__ labels,
    const float* __restrict__ cgw, const float* __restrict__ cbw,
    float* __restrict__ wpa,
    const float* __restrict__ ssw, __bf16* __restrict__ wspb,
    __bf16* __restrict__ Aav) {
  __shared__ __align__(16) char smem[16*401*4];
  int blk = blockIdx.x;
  if (blk < 2048) {                       // ---- instance-norm stats
    int bc = blk;
    const float4* p = (const float4*)(x + (size_t)bc * 4096);
    float s = 0.f, ss = 0.f;
    for (int i = threadIdx.x; i < 1024; i += 256) {
      float4 v = p[i];
      s  += v.x + v.y + v.z + v.w;
      ss += v.x*v.x + v.y*v.y + v.z*v.z + v.w*v.w;
    }
    #pragma unroll
    for (int o = 32; o > 0; o >>= 1) { s += __shfl_down(s, o); ss += __shfl_down(ss, o); }
    float* sh = (float*)smem;
    int wv = threadIdx.x >> 6;
    if ((threadIdx.x & 63) == 0) { sh[wv] = s; sh[4 + wv] = ss; }
    __syncthreads();
    if (threadIdx.x == 0) {
      float S = sh[0]+sh[1]+sh[2]+sh[3], SS = sh[4]+sh[5]+sh[6]+sh[7];
      float m = S * (1.f/4096.f);
      float var = SS * (1.f/4096.f) - m*m;
      stats[bc] = m;
      stats[2048 + bc] = rsqrtf(var + 1e-5f);
    }
  } else if (blk < 2176) {                // ---- labels (last one-hot j)
    int idx = (blk - 2048)*256 + threadIdx.x;       // 0..32767
    int b = idx >> 12, pix = idx & 4095;
    const float* p = seg + (size_t)b*19*4096 + pix;
    int lab = -1;
    for (int j = 0; j < 19; ++j) if (p[(size_t)j*4096] > 0.f) lab = j;
    labels[idx] = lab;
  } else if (blk < 3200) {                // ---- pack avg weights wpa[k5][c][n]
    int bid = blk - 2176;
    float* s = (float*)smem;
    int n0 = (bid & 31) * 16, c0 = (bid >> 5) * 16;
    for (int i = threadIdx.x; i < 6400; i += 256) {
      int nn = i / 400, qq = i % 400;
      int n = n0 + nn;
      const float* src = (n < 256) ? cgw + (size_t)n*12800 : cbw + (size_t)(n-256)*12800;
      s[nn*401 + qq] = src[c0*25 + qq];
    }
    __syncthreads();
    for (int i = threadIdx.x; i < 6400; i += 256) {
      int nn = i & 15, rest = i >> 4;
      int k5 = rest % 25, cc = rest / 25;
      wpa[((size_t)k5*512 + c0 + cc)*512 + n0 + nn] = s[nn*401 + cc*25 + k5];
    }
  } else if (blk < 4200) {                // ---- pack shared weights (j=19 zero)
    int idx = (blk - 3200)*256 + threadIdx.x;       // < 256000
    int o = idx & 511, k5 = (idx >> 9) % 25, j = idx / 12800;
    wspb[idx] = (j < 19) ? (__bf16)ssw[((size_t)o*19 + j)*25 + k5] : (__bf16)0.f;
  } else {                                // ---- Aav zero row 3800
    ((unsigned*)(Aav + 3800ull*512))[threadIdx.x] = 0;   // 256 dwords = 1024 B
  }
}

// ---------------- mu[b,j,e] = relu(sum_d sc[b,j,d]*fc_w[j,e,d] + fc_b) ------
__global__ __launch_bounds__(512) void k_mu(const float* __restrict__ sc,
                                            const float* __restrict__ fcw,
                                            const float* __restrict__ fcb,
                                            float* __restrict__ mu) {
  int b = blockIdx.x / 19, j = blockIdx.x % 19;
  __shared__ float s[512];
  s[threadIdx.x] = sc[(b*19 + j)*512 + threadIdx.x];
  __syncthreads();
  int e = threadIdx.x;
  const float4* w4 = (const float4*)(fcw + ((size_t)(j*512 + e))*512);
  const float4* s4 = (const float4*)s;
  float acc = 0.f;
  for (int d = 0; d < 128; ++d) {
    float4 w = w4[d], v = s4[d];
    acc += w.x*v.x + w.y*v.y + w.z*v.z + w.w*v.w;
  }
  acc += fcb[j*512 + e];
  mu[(b*19 + j)*512 + e] = fmaxf(acc, 0.f);
}

// ---- pack spade weights -> fp8 e4m3, fixed scale x2^6: wq[k5][n][c] --------
__global__ __launch_bounds__(256) void k_pack_spade(
    const float* __restrict__ g, const float* __restrict__ bt,
    uint8_t* __restrict__ wq) {
  int n = blockIdx.x;                               // 0..511
  const float* src = (n < 256) ? g + (size_t)n*12800 : bt + (size_t)(n-256)*12800;
  __shared__ float s[12800];
  for (int i = threadIdx.x; i < 12800; i += 256) s[i] = src[i];
  __syncthreads();
  int t = threadIdx.x;
  for (int k5 = 0; k5 < 25; ++k5) {
    float w0 = s[(2*t)*25 + k5] * 64.f, w1 = s[(2*t+1)*25 + k5] * 64.f;
    int pk = __builtin_amdgcn_cvt_pk_fp8_f32(w0, w1, 0, false);
    *(unsigned short*)(wq + ((size_t)k5*512 + n)*512 + 2*t) = (unsigned short)pk;
  }
}

// ---- A[b,j,k5,n] = sum_c mu[b,j,c]*wpa[k5][c][n]  (mu via scalar loads) ----
__global__ __launch_bounds__(512) void k_A_avg(const float* __restrict__ mu,
                                               const float* __restrict__ wpa,
                                               __bf16* __restrict__ A) {
  int b = blockIdx.x / 25, k5 = blockIdx.x % 25;
  int n = threadIdx.x;
  const float* wp = wpa + (size_t)k5*262144 + n;
  const float* mub = mu + b*19*512;                 // wave-uniform rows -> s_load
  float acc[19];
  #pragma unroll
  for (int j = 0; j < 19; ++j) acc[j] = 0.f;
  for (int c = 0; c < 512; ++c) {
    float w = wp[(size_t)c*512];
    #pragma unroll
    for (int j = 0; j < 19; ++j) acc[j] += mub[j*512 + c] * w;
  }
  #pragma unroll
  for (int j = 0; j < 19; ++j)
    A[((size_t)((b*19 + j)*25 + k5))*512 + n] = (__bf16)acc[j];
}

// ---- actv: debranched gather -> fp8 e4m3 (x2^8) NHWC padded ----------------
// Writes its own zero borders (rows hp<2, hp>=66 and cols wp in {0,1,66,67}).
__global__ void k_actv(const int* __restrict__ labels, const __bf16* __restrict__ wsp,
                       const float* __restrict__ ssb, uint8_t* __restrict__ actv) {
  int b = blockIdx.x / 68, hp = blockIdx.x % 68;
  int t = threadIdx.x;
  size_t rowbase = ((size_t)b*68 + hp)*68;          // padded pixel index base
  if (hp < 2 || hp >= 66) {                         // full zero row
    unsigned* dp = (unsigned*)(actv + rowbase*512);
    for (int i = t; i < 8704; i += 256) dp[i] = 0;
    return;
  }
  int h = hp - 2;
  __shared__ int lab[5*68];
  for (int i = t; i < 5*68; i += 256) {
    int dh = i / 68, xx = i % 68;
    int hh = h + dh - 2, ww = xx - 2;
    int l = 19;
    if (hh >= 0 && hh < 64 && ww >= 0 && ww < 64) {
      int l0 = labels[b*4096 + hh*64 + ww];
      if (l0 >= 0) l = l0;
    }
    lab[i] = l;
  }
  {                                                 // left/right border pixels
    unsigned* dp = (unsigned*)(actv + rowbase*512);
    dp[t] = 0; dp[66*128 + t] = 0;                  // pixels 0,1 and 66,67
  }
  __syncthreads();
  float bs0 = ssb[2*t], bs1 = ssb[2*t + 1];
  for (int w = 0; w < 64; ++w) {
    float a0 = bs0, a1 = bs1;
    #pragma unroll
    for (int tap = 0; tap < 25; ++tap) {
      int l = lab[(tap/5)*68 + w + (tap%5)];        // wave-uniform
      bf16x2 v = *(const bf16x2*)(wsp + (size_t)(l*25 + tap)*512 + 2*t);
      a0 += (float)v[0]; a1 += (float)v[1];
    }
    a0 = fmaxf(a0, 0.f) * 256.f;
    a1 = fmaxf(a1, 0.f) * 256.f;
    int pk = __builtin_amdgcn_cvt_pk_fp8_f32(a0, a1, 0, false);
    *(unsigned short*)(actv + (rowbase + 2 + w)*512 + 2*t) = (unsigned short)pk;
  }
}

// ---- implicit-GEMM conv, MXFP8 fixed-scale: M=32768, N=512, K=12800 --------
// R5: two-group ping-pong. 256x256 tile, 8 waves; g0 = waves 0-3 (rows
// 0-127), g1 = waves 4-7 (rows 128-255) -- one wave of each group per SIMD.
// Per K=64 chunk (mfma_scale_f32_32x32x64), two barrier phases:
//   phase A: g0 reads frags(t) | g1 MFMAs chunk t-1   -> LDS & MFMA pipes
//   phase B: g0 MFMAs chunk t  | g1 reads frags(t)       both busy always
// 3-deep LDS buffers (96 KB) so staging (issued phase B, counted vmcnt(4),
// never drained) never collides with the mid-MFMA transient A-reads.
// lgkmcnt(0) before every barrier: reads serviced before any restage.
__global__ __launch_bounds__(512) void k_conv(
    const uint8_t* __restrict__ actv, const uint8_t* __restrict__ wq,
    const float* __restrict__ sgb, const float* __restrict__ sbb,
    __bf16* __restrict__ gbs) {
  __shared__ __align__(16) uint8_t ldsA[3][16384];  // 256 rows x 64 B
  __shared__ __align__(16) uint8_t ldsB[3][16384];
  const int tid = threadIdx.x, wv = tid >> 6, lane = tid & 63;
  const int l31 = lane & 31, hh = lane >> 5;        // operand row / K-half
  const int m0 = blockIdx.x * 256, n0 = blockIdx.y * 256;
  const int b = m0 >> 12;
  const int g = wv >> 2;                            // ping-pong group
  const int wm = g * 128, wn = (wv & 3) * 64;

  // staging: 1024 16B-slots per tile, 2 per thread; source pre-swizzled so
  // LDS stays linear (slot s holds logical K-chunk s^(r&3)).
  int aoff[2], boff[2], ldso[2];
  #pragma unroll
  for (int i = 0; i < 2; ++i) {
    int p = i*512 + tid;
    int r = p >> 2, s = p & 3;
    int c = s ^ (r & 3);
    int pix = (m0 + r) & 4095;
    int h = pix >> 6, w = pix & 63;
    aoff[i] = ((b*68 + h)*68 + w)*512 + c*16;
    boff[i] = (n0 + r)*512 + c*16;
    ldso[i] = i*8192 + wv*1024;                     // wave-uniform base
  }

  f32x16 acc[4][2] = {};
  v8i bfr[2], af01[2];

  // stage K-chunk t (t = k5*8 + kc, K=64) into buffer `buf` (4 vmem/wave)
  auto stage = [&](int t, int buf) {
    int k5 = t >> 3, kc = t & 7;
    int a_k = ((k5/5)*68 + (k5%5))*512 + kc*64;
    int b_k = k5*262144 + kc*64;
    #pragma unroll
    for (int i = 0; i < 2; ++i) {
      gl_lds16(actv + aoff[i] + a_k, &ldsA[buf][0] + ldso[i]);
      gl_lds16(wq   + boff[i] + b_k, &ldsB[buf][0] + ldso[i]);
    }
  };

  // one 32-row operand fragment: lane -> row l31, K-bytes hh*32..+31
  auto afrag = [&](int buf, int mi) -> v8i {
    int r = wm + mi*32 + l31;
    const uint8_t* base = &ldsA[buf][r*64];
    union { v8i v; uint4 u[2]; } tt;
    tt.u[0] = *(const uint4*)(base + ((2*hh    ) ^ (l31 & 3))*16);
    tt.u[1] = *(const uint4*)(base + ((2*hh + 1) ^ (l31 & 3))*16);
    return tt.v;
  };
  auto bfrag = [&](int buf, int ni) -> v8i {
    int r = wn + ni*32 + l31;
    const uint8_t* base = &ldsB[buf][r*64];
    union { v8i v; uint4 u[2]; } tt;
    tt.u[0] = *(const uint4*)(base + ((2*hh    ) ^ (l31 & 3))*16);
    tt.u[1] = *(const uint4*)(base + ((2*hh + 1) ^ (l31 & 3))*16);
    return tt.v;
  };

  auto readPhase = [&](int buf) {                   // 8 x ds_read_b128, held
    bfr[0]  = bfrag(buf, 0); bfr[1]  = bfrag(buf, 1);
    af01[0] = afrag(buf, 0); af01[1] = afrag(buf, 1);
  };
  auto mfmaPhase = [&](int buf) {                   // 8 MFMA + 4 transient reads
    __builtin_amdgcn_s_setprio(1);
    #pragma unroll
    for (int mi = 0; mi < 2; ++mi)
      #pragma unroll
      for (int ni = 0; ni < 2; ++ni)
        acc[mi][ni] = __builtin_amdgcn_mfma_scale_f32_32x32x64_f8f6f4(
            af01[mi], bfr[ni], acc[mi][ni], 0, 0, 0, SCALE_A_DW, 0, SCALE_B_DW);
    __builtin_amdgcn_s_setprio(0);
    v8i af2 = afrag(buf, 2), af3 = afrag(buf, 3);
    __builtin_amdgcn_s_setprio(1);
    #pragma unroll
    for (int ni = 0; ni < 2; ++ni) {
      acc[2][ni] = __builtin_amdgcn_mfma_scale_f32_32x32x64_f8f6f4(
          af2, bfr[ni], acc[2][ni], 0, 0, 0, SCALE_A_DW, 0, SCALE_B_DW);
      acc[3][ni] = __builtin_amdgcn_mfma_scale_f32_32x32x64_f8f6f4(
          af3, bfr[ni], acc[3][ni], 0, 0, 0, SCALE_A_DW, 0, SCALE_B_DW);
    }
    __builtin_amdgcn_s_setprio(0);
  };

  stage(0, 0); stage(1, 1);                         // 8 vmem in flight
  #pragma unroll 1
  for (int t = 0; t < 200; ++t) {
    int buf = t % 3;
    asm volatile("s_waitcnt vmcnt(4)" ::: "memory");     // stage(t) landed
    asm volatile("s_waitcnt lgkmcnt(0)" ::: "memory");   // prev reads serviced
    __builtin_amdgcn_s_barrier();                        // === phase A(t) ===
    if (g == 0) readPhase(buf);
    else if (t > 0) mfmaPhase((t + 2) % 3);              // chunk t-1's buffer
    asm volatile("s_waitcnt lgkmcnt(0)" ::: "memory");
    __builtin_amdgcn_s_barrier();                        // === phase B(t) ===
    stage(t + 2 <= 199 ? t + 2 : 199, (t + 2) % 3);      // restage t-1's buf
    if (g == 0) mfmaPhase(buf);
    else readPhase(buf);
  }
  asm volatile("s_waitcnt lgkmcnt(0)" ::: "memory");
  __builtin_amdgcn_s_barrier();
  if (g == 1) mfmaPhase(199 % 3);                        // finish chunk 199

  // epilogue: 32x32 C-layout row=(j&3)+8*(j>>2)+4*hh, col=l31
  #pragma unroll
  for (int ni = 0; ni < 2; ++ni) {
    int n = n0 + wn + ni*32 + l31;
    float bias = (n < 256) ? sgb[n] : sbb[n - 256];
    #pragma unroll
    for (int mi = 0; mi < 4; ++mi) {
      #pragma unroll
      for (int j = 0; j < 16; ++j) {
        int row = (j & 3) + 8*(j >> 2) + 4*hh;
        int m = m0 + wm + mi*32 + row;
        gbs[(size_t)m*512 + n] = (__bf16)(acc[mi][ni][j] + bias);
      }
    }
  }
}

// ---- fused avg-gather + blend/instance-norm/NCHW-store ---------------------
// Phase 1 (thread = channel pair): 25-tap gather of gamma/beta_avg for 16
// pixels -> LDS; stage matching gbs tile -> LDS (coalesced).
// Phase 2 (thread = channel): blend avg/spade, normalize x, write out NCHW.
__global__ __launch_bounds__(256) void k_gf(
    const int* __restrict__ labels, const __bf16* __restrict__ A,
    const float* __restrict__ cgb, const float* __restrict__ cbb,
    const __bf16* __restrict__ gbs, const float* __restrict__ x,
    const float* __restrict__ stats, const float* __restrict__ blg,
    const float* __restrict__ blb, float* __restrict__ out) {
  int wt = blockIdx.x & 3, h = (blockIdx.x >> 2) & 63, b = blockIdx.x >> 8;
  int w0 = wt * 16;
  __shared__ int rowbase[5*20];
  __shared__ __bf16 avg[16][512];
  __shared__ __bf16 spd[16][512];
  for (int i = threadIdx.x; i < 100; i += 256) {
    int dh = i / 20, xx = i % 20;
    int hh = h + dh - 2, ww = w0 + xx - 2;
    int l = (hh >= 0 && hh < 64 && ww >= 0 && ww < 64) ? labels[b*4096 + hh*64 + ww] : -1;
    rowbase[i] = (l >= 0) ? (b*19 + l)*25 : -1;
  }
  __syncthreads();
  int t = threadIdx.x;
  float bs0, bs1;
  if (2*t < 256) { bs0 = cgb[2*t]; bs1 = cgb[2*t + 1]; }
  else           { bs0 = cbb[2*t - 256]; bs1 = cbb[2*t - 255]; }
  size_t pixb = (size_t)b*4096 + h*64 + w0;
  for (int px = 0; px < 16; ++px) {
    float a0 = bs0, a1 = bs1;
    #pragma unroll
    for (int tap = 0; tap < 25; ++tap) {
      int rb = rowbase[(tap/5)*20 + px + (tap%5)];
      int row = (rb >= 0) ? rb + tap : 3800;
      bf16x2 v = *(const bf16x2*)(A + (size_t)row*512 + 2*t);
      a0 += (float)v[0]; a1 += (float)v[1];
    }
    avg[px][2*t]     = (__bf16)a0;
    avg[px][2*t + 1] = (__bf16)a1;
    *(bf16x2*)&spd[px][2*t] = *(const bf16x2*)(gbs + (pixb + px)*512 + 2*t);
  }
  __syncthreads();
  float ga = 1.f / (1.f + expf(-blg[0]));
  float ba = 1.f / (1.f + expf(-blb[0]));
  int c = threadIdx.x;                               // 0..255
  int bc = b*256 + c;
  float mean = stats[bc], rstd = stats[2048 + bc];
  size_t xb = (size_t)bc*4096 + h*64 + w0;
  #pragma unroll
  for (int pq = 0; pq < 4; ++pq) {
    float4 xv = *(const float4*)(x + xb + pq*4);
    float4 ov;
    float* xo = (float*)&xv; float* oo = (float*)&ov;
    #pragma unroll
    for (int j = 0; j < 4; ++j) {
      int px = pq*4 + j;
      float gf  = ga*(float)avg[px][c]       + (1.f - ga)*(float)spd[px][c];
      float bf_ = ba*(float)avg[px][256 + c] + (1.f - ba)*(float)spd[px][256 + c];
      oo[j] = (xo[j] - mean)*rstd*(1.f + gf) + bf_;
    }
    *(float4*)(out + xb + pq*4) = ov;
  }
}

extern "C" void kernel_launch(void* const* d_in, const int* in_sizes, int n_in,
                              void* d_out, int out_size, void* d_ws, size_t ws_size,
                              hipStream_t stream) {
  const float* x    = (const float*)d_in[0];
  const float* seg  = (const float*)d_in[1];
  const float* sc   = (const float*)d_in[2];
  const float* fcw  = (const float*)d_in[3];
  const float* fcb  = (const float*)d_in[4];
  const float* cgw  = (const float*)d_in[5];
  const float* cgb  = (const float*)d_in[6];
  const float* cbw  = (const float*)d_in[7];
  const float* cbb  = (const float*)d_in[8];
  const float* ssw  = (const float*)d_in[9];
  const float* ssb  = (const float*)d_in[10];
  const float* sgw  = (const float*)d_in[11];
  const float* sgb  = (const float*)d_in[12];
  const float* sbw  = (const float*)d_in[13];
  const float* sbb  = (const float*)d_in[14];
  const float* blg  = (const float*)d_in[15];
  const float* blb  = (const float*)d_in[16];
  float* out = (float*)d_out;

  char* ws = (char*)d_ws;
  size_t off = 0;
  auto alloc = [&](size_t bytes) {
    void* p = ws + off; off += (bytes + 255) & ~(size_t)255; return p;
  };
  float*   stats = (float*)alloc(2048ull*2*4);
  int*     labels= (int*)  alloc(32768ull*4);
  float*   mu    = (float*)alloc(77824ull*4);
  __bf16*  Aav   = (__bf16*)alloc((3800ull + 1)*512*2);  // + zero row 3800
  __bf16*  wspb  = (__bf16*)alloc(20ull*25*512*2);       // j=19 zero rows
  float*   wpa   = (float*)alloc(25ull*512*512*4);       // 26.2 MB
  uint8_t* wq    = (uint8_t*)alloc(25ull*512*512);       // 6.6 MB fp8
  uint8_t* actv  = (uint8_t*)alloc(8ull*68*68*512);      // 18.9 MB fp8 NHWC pad
  __bf16*  gbs   = (__bf16*)alloc(8ull*4096*512*2);      // 33.5 MB (NHWC)

  k_prep      <<<4201, 256, 0, stream>>>(x, stats, seg, labels, cgw, cbw, wpa, ssw, wspb, Aav);
  k_mu        <<<152, 512, 0, stream>>>(sc, fcw, fcb, mu);
  k_pack_spade<<<512, 256, 0, stream>>>(sgw, sbw, wq);
  k_A_avg     <<<200, 512, 0, stream>>>(mu, wpa, Aav);
  k_actv      <<<544, 256, 0, stream>>>(labels, wspb, ssb, actv);
  k_conv      <<<dim3(128, 2), 512, 0, stream>>>(actv, wq, sgb, sbb, gbs);
  k_gf        <<<2048, 256, 0, stream>>>(labels, Aav, cgb, cbb, gbs, x, stats, blg, blb, out);
}